// Round 7
// baseline (318.666 us; speedup 1.0000x reference)
//
#include <hip/hip_runtime.h>
#include <hip/hip_bf16.h>

#define B_  16
#define S_  1024
#define H_  768
#define NH_ 12
#define HD_ 64
#define BS_ (B_*S_)   // 16384
#define WROWS_ 589824 // 768*768 per weight matrix

typedef __bf16 bfx8 __attribute__((ext_vector_type(8)));
typedef __bf16 bfx4 __attribute__((ext_vector_type(4)));
typedef __bf16 bfx2 __attribute__((ext_vector_type(2)));
typedef float  f32x4 __attribute__((ext_vector_type(4)));
typedef float  f32x16 __attribute__((ext_vector_type(16)));
typedef unsigned u32x2 __attribute__((ext_vector_type(2)));
typedef unsigned u32x4 __attribute__((ext_vector_type(4)));

#define MFMA(a,b,c)   __builtin_amdgcn_mfma_f32_16x16x32_bf16(a,b,c,0,0,0)
#define MFMA32(a,b,c) __builtin_amdgcn_mfma_f32_32x32x16_bf16(a,b,c,0,0,0)

__device__ __forceinline__ float fast_exp2(float x) {
#if __has_builtin(__builtin_amdgcn_exp2f)
    return __builtin_amdgcn_exp2f(x);
#else
    return exp2f(x);
#endif
}

// async global->LDS, 16B per lane; LDS dest = wave-uniform base + lane*16
__device__ __forceinline__ void async_cp16(const __bf16* g, __bf16* l) {
    __builtin_amdgcn_global_load_lds(
        (const __attribute__((address_space(1))) unsigned int*)g,
        (__attribute__((address_space(3))) unsigned int*)l,
        16, 0, 0);
}

// pack two f32 -> one u32 of 2 bf16 (elem0 = low 16b)
__device__ __forceinline__ unsigned pk2(float a, float b) {
    bfx2 t; t[0] = (__bf16)a; t[1] = (__bf16)b;
    return __builtin_bit_cast(unsigned, t);
}

// v_permlane32_swap_b32: a.hi(lanes>=32) <-> b.lo(lanes<32).
__device__ __forceinline__ void pl32swap(unsigned &a, unsigned &b) {
#if __has_builtin(__builtin_amdgcn_permlane32_swap)
    u32x2 r = __builtin_amdgcn_permlane32_swap(a, b, 0, 0);
    a = r[0]; b = r[1];
#else
    asm volatile("v_permlane32_swap_b32 %0, %1" : "+v"(a), "+v"(b));
#endif
}

#define LOG2E 1.4426950408889634f
#define C1    (0.125f * LOG2E)     // score scale folded with log2(e)
#define SMAX  12.0f                // static softmax offset (exp2 domain)

// ---------------------------------------------------------------------------
// Pre-cast: hidden fp32 -> bf16 (hbf), [qw|kw|vw|ow] fp32 -> bf16 (wbuf).
// ---------------------------------------------------------------------------
__global__ __launch_bounds__(256) void precast(
    const float* __restrict__ hidden,
    const float* __restrict__ qw, const float* __restrict__ kw,
    const float* __restrict__ vw, const float* __restrict__ ow,
    __bf16* __restrict__ hbf, __bf16* __restrict__ wbuf)
{
    const int tid = threadIdx.x;
    const int bid = blockIdx.x;
    if (bid < 6144) {
        const long base = ((long)bid * 256 + tid) * 8;
        f32x4 a = *(const f32x4*)(hidden + base);
        f32x4 b = *(const f32x4*)(hidden + base + 4);
        bfx8 o;
        #pragma unroll
        for (int j = 0; j < 4; ++j) { o[j] = (__bf16)a[j]; o[4 + j] = (__bf16)b[j]; }
        *(bfx8*)(hbf + base) = o;
    } else {
        const long e = ((long)(bid - 6144) * 256 + tid) * 8;
        const int kind = (int)(e / WROWS_);
        const float* src = kind == 0 ? qw : kind == 1 ? kw : kind == 2 ? vw : ow;
        const long off = e - (long)kind * WROWS_;
        f32x4 a = *(const f32x4*)(src + off);
        f32x4 b = *(const f32x4*)(src + off + 4);
        bfx8 o;
        #pragma unroll
        for (int j = 0; j < 4; ++j) { o[j] = (__bf16)a[j]; o[4 + j] = (__bf16)b[j]; }
        *(bfx8*)(wbuf + e) = o;
    }
}

// ---------------------------------------------------------------------------
// Fused QKV GEMM. 128x128 tile, BK=64, swizzled global_load_lds staging.
// (round-4 serial-staging version — known-good)
// ---------------------------------------------------------------------------
__global__ __launch_bounds__(512, 4) void qkv_gemm(
    const __bf16* __restrict__ hbf, const __bf16* __restrict__ wbuf,
    const float* __restrict__ qb, const float* __restrict__ kb,
    const float* __restrict__ vb,
    __bf16* __restrict__ qo, __bf16* __restrict__ ko, __bf16* __restrict__ vto)
{
    __shared__ __bf16 smem[18432];      // 36864 B: As|Bs in [0,16384), Ts all
    __bf16* As = smem;                  // 8192 elems
    __bf16* Bs = smem + 8192;           // 8192 elems
    __bf16* Ts = smem;                  // epilogue: 8 waves x 2304 elems

    const int bid  = blockIdx.x;
    const int xcd  = bid & 7;
    const int slot = bid >> 3;          // 0..287
    const int xx   = slot >> 4;         // 0..17  (n-tile / weight panel)
    const int yy   = xcd * 16 + (slot & 15);   // 0..127 (m-tile)

    const int tid  = threadIdx.x;
    const int lane = tid & 63, wid = tid >> 6;
    const int quad = lane >> 4, l16 = lane & 15;
    const int n0g = xx * 128;
    const int m0  = yy * 128;
    const int wm = (wid & 3) * 32;      // s-slice (4)
    const int wn = (wid >> 2) * 64;     // d-slice (2)
    const int kind = xx / 6;            // 0=Q,1=K,2=V
    const int nl0  = n0g - kind * 768;

    // acc: Q/K -> [dt][st] flat dt*2+st ; V -> [st][dt] flat st*4+dt
    f32x4 acc[8];
    #pragma unroll
    for (int i = 0; i < 8; ++i)
        #pragma unroll
        for (int r = 0; r < 4; ++r) acc[i][r] = 0.0f;

    const int drow = lane >> 3;
    const int dcol = ((lane & 7) ^ (drow & 7)) * 8;
    const __bf16* Ag0 = hbf  + (long)(m0  + drow) * H_ + dcol;
    const __bf16* Bg0 = wbuf + (long)(n0g + drow) * H_ + dcol;
    const int swz = (l16 & 7);

    for (int kt = 0; kt < 12; ++kt) {
        __syncthreads();
        const int k0 = kt * 64;
        #pragma unroll
        for (int c = 0; c < 2; ++c) {
            const int cc = wid * 2 + c;       // chunk 0..15 (8 rows each)
            async_cp16(Ag0 + (long)cc * 8 * H_ + k0, As + cc * 512);
            async_cp16(Bg0 + (long)cc * 8 * H_ + k0, Bs + cc * 512);
        }
        __syncthreads();
        #pragma unroll
        for (int ks = 0; ks < 2; ++ks) {
            const int coff = ((ks * 4 + quad) ^ swz) * 8;
            bfx8 af[2], bb[4];
            #pragma unroll
            for (int t = 0; t < 2; ++t)
                af[t] = *(const bfx8*)(As + (wm + t * 16 + l16) * 64 + coff);
            #pragma unroll
            for (int t = 0; t < 4; ++t)
                bb[t] = *(const bfx8*)(Bs + (wn + t * 16 + l16) * 64 + coff);
            if (kind < 2) {
                #pragma unroll
                for (int dt = 0; dt < 4; ++dt)
                    #pragma unroll
                    for (int st = 0; st < 2; ++st)
                        acc[dt * 2 + st] = MFMA(bb[dt], af[st], acc[dt * 2 + st]);
            } else {
                #pragma unroll
                for (int st = 0; st < 2; ++st)
                    #pragma unroll
                    for (int dt = 0; dt < 4; ++dt)
                        acc[st * 4 + dt] = MFMA(af[st], bb[dt], acc[st * 4 + dt]);
            }
        }
    }

    __syncthreads();                    // As/Bs dead -> Ts reuse safe
    const int b  = m0 >> 10;
    const int hq = (nl0 + wn) >> 6;
    const int s_base = (m0 & 1023) + wm;

    if (kind < 2) {
        __bf16* Tw = Ts + wid * 2304;   // 32 x 72 tile [s][d]
        const float* bias = (kind == 0) ? qb : kb;
        __bf16* outp = (kind == 0) ? qo : ko;
        // acc[dt*2+st]: row=d=dt*16+quad*4+r, col=s=st*16+l16
        #pragma unroll
        for (int dt = 0; dt < 4; ++dt) {
            f32x4 bv = *(const f32x4*)(bias + nl0 + wn + dt * 16 + quad * 4);
            #pragma unroll
            for (int st = 0; st < 2; ++st) {
                bfx4 pk;
                #pragma unroll
                for (int r = 0; r < 4; ++r)
                    pk[r] = (__bf16)(acc[dt * 2 + st][r] + bv[r]);
                *(bfx4*)(Tw + (st * 16 + l16) * 72 + dt * 16 + quad * 4) = pk;
            }
        }
        __bf16* op = outp + ((((long)(b * NH_ + hq)) << 10) + s_base) * HD_;
        const int srow = lane >> 3, c8 = (lane & 7) * 8;
        #pragma unroll
        for (int i = 0; i < 4; ++i) {
            const int row = i * 8 + srow;                     // 0..31
            bfx8 vv = *(const bfx8*)(Tw + row * 72 + c8);
            *(bfx8*)(op + row * HD_ + c8) = vv;               // 1KB linear/instr
        }
    } else {
        __bf16* Tw = Ts + wid * 2304;   // 64 x 36 tile [d][s]
        // acc[st*4+dt]: row=s=st*16+quad*4+r, col=d=dt*16+l16
        #pragma unroll
        for (int dt = 0; dt < 4; ++dt) {
            const float bv = vb[nl0 + wn + dt * 16 + l16];
            #pragma unroll
            for (int st = 0; st < 2; ++st) {
                bfx4 pk;
                #pragma unroll
                for (int r = 0; r < 4; ++r)
                    pk[r] = (__bf16)(acc[st * 4 + dt][r] + bv);
                *(bfx4*)(Tw + (dt * 16 + l16) * 36 + st * 16 + quad * 4) = pk;
            }
        }
        __bf16* op = vto + (((long)(b * NH_ + hq) * HD_) << 10);
        #pragma unroll
        for (int i = 0; i < 4; ++i) {
            const int d = i * 16 + (lane >> 2);
            const int s8 = (lane & 3) * 8;
            bfx8 vv = *(const bfx8*)(Tw + d * 36 + s8);
            *(bfx8*)(op + ((long)d << 10) + s_base + s8) = vv;
        }
    }
}

// ---------------------------------------------------------------------------
// Attention, S^T formulation, 32x32x16 MFMA, P in registers.
// Round 7: occupancy via SMALL INDEPENDENT BLOCKS, not launch_bounds.
//  - 256-thread blocks (4 waves x 32 q = 128 q-rows), qc = 0..7,
//    grid = 8*12*16 = 1536 blocks.
//  - single-buffered 64-key K/V staging -> LDS 20 KB/block -> LDS permits
//    8 blocks/CU; grid/CU = 6 -> ALL blocks co-resident, zero tail,
//    24 waves/CU. Cross-block TLP fills each block's barrier/drain stalls
//    (m114 overlap), which per-wave pipelining (r6) could not.
//  - launch_bounds(256,4): VGPR cap 128, ZERO spill risk (demand ~52-64);
//    occupancy comes from actual low usage, not a forced cap (r1/r5 lesson).
//  - inner body = round-4 proven 64-key code; lacc vectorized f32x4.
// ---------------------------------------------------------------------------
__global__ __launch_bounds__(256, 4) void attn_kernel(
    const __bf16* __restrict__ q, const __bf16* __restrict__ k,
    const __bf16* __restrict__ vT, const float* __restrict__ mask,
    __bf16* __restrict__ ctx)
{
    __shared__ __bf16 Ks[4096];         // [64 key][64 d] swz   8 KB
    __shared__ __bf16 Vs[4096];         // [64 d][64 key] swz   8 KB
    __shared__ float  Ms[1024];         // mask*log2e - SMAX    4 KB

    const int tid  = threadIdx.x;
    const int lane = tid & 63, wid = tid >> 6;       // wid 0..3
    const int l32  = lane & 31, hi = lane >> 5;
    const int qc = blockIdx.x, h = blockIdx.y, b = blockIdx.z;

    const long base = ((long)(b * NH_ + h)) << 16;   // * S_ * HD_
    const __bf16* qh = q  + base;
    const __bf16* kh = k  + base;
    const __bf16* vh = vT + base;
    const float*  mb = mask + b * S_;

    #pragma unroll
    for (int i = 0; i < 4; ++i)
        Ms[tid + i * 256] = mb[tid + i * 256] * LOG2E - SMAX;

    const int qrow = qc * 128 + wid * 32 + l32;
    bfx8 qf[4];                         // B-frag: n=q=l32, k=ks*16+hi*8+0..7
    #pragma unroll
    for (int ks = 0; ks < 4; ++ks)
        qf[ks] = *(const bfx8*)(qh + (long)qrow * HD_ + ks * 16 + hi * 8);

    f32x16 o[2];                        // [dtile]: d=dtile*32+(r&3)+8*(r>>2)+4hi
    #pragma unroll
    for (int dt = 0; dt < 2; ++dt)
        #pragma unroll
        for (int r = 0; r < 16; ++r) o[dt][r] = 0.0f;
    f32x4 lacc4 = { 0.0f, 0.0f, 0.0f, 0.0f };

    // staging geometry: chunk = 1KB (8 rows x 128B), row-local swizzle
    const int r8  = lane >> 3;                 // row within chunk (0..7)
    const int c8  = ((lane & 7) ^ r8) * 8;     // pre-swizzled 16B col group
    const int sw5 = l32 & 7;

    for (int kt = 0; kt < 16; ++kt) {
        __syncthreads();                // prior compute done reading LDS
        #pragma unroll
        for (int c = 0; c < 2; ++c) {
            const int cc = wid * 2 + c;         // chunk 0..7
            async_cp16(kh + (long)(kt * 64 + cc * 8 + r8) * HD_ + c8,
                       Ks + cc * 512);
            async_cp16(vh + (long)(cc * 8 + r8) * S_ + kt * 64 + c8,
                       Vs + cc * 512);
        }
        __syncthreads();                // vmcnt(0) drain: tile ready

        #pragma unroll
        for (int t = 0; t < 2; ++t) {           // 32-key tiles
            // ---- QK^T: 4 MFMA over dk=64 ----
            f32x16 sc;
            #pragma unroll
            for (int r = 0; r < 16; ++r) sc[r] = 0.0f;
            __builtin_amdgcn_s_setprio(1);
            #pragma unroll
            for (int ks = 0; ks < 4; ++ks) {
                bfx8 kf = *(const bfx8*)(Ks + (t * 32 + l32) * 64 +
                                         (((ks * 2 + hi) ^ sw5) * 8));
                sc = MFMA32(kf, qf[ks], sc);
            }
            __builtin_amdgcn_s_setprio(0);

            // ---- softmax (static offset) + pack to bf16 words ----
            unsigned c[8];
            #pragma unroll
            for (int j = 0; j < 4; ++j) {
                const f32x4 mv = *(const f32x4*)(&Ms[kt * 64 + t * 32 +
                                                    j * 8 + hi * 4]);
                f32x4 p;
                p[0] = fast_exp2(sc[4*j+0] * C1 + mv[0]);
                p[1] = fast_exp2(sc[4*j+1] * C1 + mv[1]);
                p[2] = fast_exp2(sc[4*j+2] * C1 + mv[2]);
                p[3] = fast_exp2(sc[4*j+3] * C1 + mv[3]);
                lacc4 += p;
                c[2*j]   = pk2(p[0], p[1]);
                c[2*j+1] = pk2(p[2], p[3]);
            }
            // redistribute lane-halves: B-frag kslice0 = (c0..c3),
            // kslice1 = (c4..c7)
            pl32swap(c[0], c[2]);
            pl32swap(c[1], c[3]);
            pl32swap(c[4], c[6]);
            pl32swap(c[5], c[7]);
            u32x4 pw0 = { c[0], c[1], c[2], c[3] };
            u32x4 pw1 = { c[4], c[5], c[6], c[7] };
            bfx8 pb[2];
            pb[0] = __builtin_bit_cast(bfx8, pw0);
            pb[1] = __builtin_bit_cast(bfx8, pw1);

            // ---- PV: o[dtile] += V^T x P, 2 kslices of 16 keys ----
            __builtin_amdgcn_s_setprio(1);
            #pragma unroll
            for (int s = 0; s < 2; ++s) {
                const int ksl = t * 2 + s;              // 0..3
                #pragma unroll
                for (int dt = 0; dt < 2; ++dt) {
                    bfx8 vf = *(const bfx8*)(Vs + (dt * 32 + l32) * 64 +
                                             (((ksl * 2 + hi) ^ sw5) * 8));
                    o[dt] = MFMA32(vf, pb[s], o[dt]);
                }
            }
            __builtin_amdgcn_s_setprio(0);
        }
    }

    // denom: lane covers half the keys for its q; partner lane^32 the rest
    float lacc = (lacc4[0] + lacc4[1]) + (lacc4[2] + lacc4[3]);
    lacc += __shfl_xor(lacc, 32);
    const float linv = 1.0f / lacc;

    __bf16* cp = ctx + ((long)(b << 10) + qrow) * H_ + h * HD_;
    #pragma unroll
    for (int dt = 0; dt < 2; ++dt) {
        #pragma unroll
        for (int j = 0; j < 4; ++j) {
            bfx4 ov;
            #pragma unroll
            for (int r = 0; r < 4; ++r)
                ov[r] = (__bf16)(o[dt][4*j+r] * linv);
            *(bfx4*)(cp + dt * 32 + j * 8 + hi * 4) = ov;
        }
    }
}

// ---------------------------------------------------------------------------
// Output projection + residual. 8 waves x (32m x 64n), XCD-chunked map.
// (round-4 serial-staging version — known-good)
// ---------------------------------------------------------------------------
__global__ __launch_bounds__(512, 4) void out_gemm(
    const __bf16* __restrict__ ctx, const __bf16* __restrict__ wbuf,
    const float* __restrict__ ob, const float* __restrict__ hidden,
    float* __restrict__ xres)
{
    __shared__ __bf16 As[128 * 64];
    __shared__ __bf16 Bs[128 * 64];

    const int bid  = blockIdx.x;
    const int xcd  = bid & 7;
    const int slot = bid >> 3;          // 0..95
    const int xx   = slot >> 4;         // 0..5
    const int yy   = xcd * 16 + (slot & 15);

    const int tid  = threadIdx.x;
    const int lane = tid & 63, wid = tid >> 6;
    const int quad = lane >> 4, l16 = lane & 15;
    const int n0 = xx * 128;
    const int m0 = yy * 128;
    const int wm = (wid & 3) * 32;
    const int wn = (wid >> 2) * 64;

    f32x4 acc[2][4];
    #pragma unroll
    for (int i = 0; i < 2; ++i)
        #pragma unroll
        for (int j = 0; j < 4; ++j)
            #pragma unroll
            for (int r = 0; r < 4; ++r) acc[i][j][r] = 0.0f;

    const int drow = lane >> 3;
    const int dcol = ((lane & 7) ^ (drow & 7)) * 8;
    const __bf16* Ag0 = ctx  + (long)(m0 + drow) * H_ + dcol;
    const __bf16* Bg0 = wbuf + (long)(3 * 768 + n0 + drow) * H_ + dcol;
    const int swz = (l16 & 7);

    for (int kt = 0; kt < 12; ++kt) {
        __syncthreads();
        const int k0 = kt * 64;
        #pragma unroll
        for (int c = 0; c < 2; ++c) {
            const int cc = wid * 2 + c;
            async_cp16(Ag0 + (long)cc * 8 * H_ + k0, As + cc * 512);
            async_cp16(Bg0 + (long)cc * 8 * H_ + k0, Bs + cc * 512);
        }
        __syncthreads();
        #pragma unroll
        for (int ks = 0; ks < 2; ++ks) {
            const int coff = ((ks * 4 + quad) ^ swz) * 8;
            bfx8 af[2], bb[4];
            #pragma unroll
            for (int t = 0; t < 2; ++t)
                af[t] = *(const bfx8*)(As + (wm + t * 16 + l16) * 64 + coff);
            #pragma unroll
            for (int t = 0; t < 4; ++t)
                bb[t] = *(const bfx8*)(Bs + (wn + t * 16 + l16) * 64 + coff);
            #pragma unroll
            for (int mt = 0; mt < 2; ++mt)
                #pragma unroll
                for (int nt = 0; nt < 4; ++nt)
                    acc[mt][nt] = MFMA(af[mt], bb[nt], acc[mt][nt]);
        }
    }

    #pragma unroll
    for (int nt = 0; nt < 4; ++nt) {
        const int n = n0 + wn + nt * 16 + l16;
        const float bv = ob[n];
        #pragma unroll
        for (int mt = 0; mt < 2; ++mt) {
            #pragma unroll
            for (int r = 0; r < 4; ++r) {
                const int m = m0 + wm + mt * 16 + quad * 4 + r;
                const long idx = (long)m * H_ + n;
                xres[idx] = acc[mt][nt][r] + bv + hidden[idx];
            }
        }
    }
}

// ---------------------------------------------------------------------------
// LayerNorm over H=768, wave per row
// ---------------------------------------------------------------------------
__global__ __launch_bounds__(256) void ln_kernel(
    const float* __restrict__ xres, const float* __restrict__ gamma,
    const float* __restrict__ beta, float* __restrict__ out)
{
    const int tid = threadIdx.x, lane = tid & 63, wid = tid >> 6;
    const long row = (long)blockIdx.x * 4 + wid;
    const float* xr = xres + row * H_;

    f32x4 xv[3];
    float sum = 0.0f, sumsq = 0.0f;
    #pragma unroll
    for (int c = 0; c < 3; ++c) {
        xv[c] = *(const f32x4*)(xr + c * 256 + lane * 4);
        #pragma unroll
        for (int j = 0; j < 4; ++j) { sum += xv[c][j]; sumsq += xv[c][j] * xv[c][j]; }
    }
    #pragma unroll
    for (int off = 1; off < 64; off <<= 1) {
        sum   += __shfl_xor(sum, off);
        sumsq += __shfl_xor(sumsq, off);
    }
    const float mean = sum * (1.0f / 768.0f);
    const float var  = sumsq * (1.0f / 768.0f) - mean * mean;
    const float rstd = rsqrtf(var + 1e-12f);

    float* orow = out + row * H_;
    #pragma unroll
    for (int c = 0; c < 3; ++c) {
        f32x4 g  = *(const f32x4*)(gamma + c * 256 + lane * 4);
        f32x4 bt = *(const f32x4*)(beta  + c * 256 + lane * 4);
        f32x4 ov;
        #pragma unroll
        for (int j = 0; j < 4; ++j) ov[j] = (xv[c][j] - mean) * rstd * g[j] + bt[j];
        *(f32x4*)(orow + c * 256 + lane * 4) = ov;
    }
}

extern "C" void kernel_launch(void* const* d_in, const int* in_sizes, int n_in,
                              void* d_out, int out_size, void* d_ws, size_t ws_size,
                              hipStream_t stream)
{
    const float* hidden = (const float*)d_in[0];
    const float* mask   = (const float*)d_in[1];
    const float* qw = (const float*)d_in[2];
    const float* qb = (const float*)d_in[3];
    const float* kw = (const float*)d_in[4];
    const float* kb = (const float*)d_in[5];
    const float* vw = (const float*)d_in[6];
    const float* vb = (const float*)d_in[7];
    const float* ow = (const float*)d_in[8];
    const float* ob = (const float*)d_in[9];
    const float* gamma = (const float*)d_in[10];
    const float* beta  = (const float*)d_in[11];
    float* out = (float*)d_out;

    // ws layout (96 MB): [0,24) hbf->ctx alias; [24,48) q; [48,72) k; [72,96) vt
    // xres fp32 aliases [24,72). wbuf bf16 weights live in d_out until ln.
    char* ws = (char*)d_ws;
    const size_t SZB = (size_t)BS_ * H_ * 2;     // 25,165,824 B per bf16 buffer
    __bf16* hbf  = (__bf16*)ws;
    __bf16* qws  = (__bf16*)(ws + SZB);
    __bf16* kws  = (__bf16*)(ws + 2 * SZB);
    __bf16* vtws = (__bf16*)(ws + 3 * SZB);
    __bf16* cws  = hbf;                          // ctx aliases hbf
    float*  xres = (float*)(ws + SZB);           // aliases q,k
    __bf16* wbuf = (__bf16*)d_out;               // scratch inside output buffer

    precast<<<dim3(7296), 256, 0, stream>>>(hidden, qw, kw, vw, ow, hbf, wbuf);
    qkv_gemm<<<dim3(2304), 512, 0, stream>>>(hbf, wbuf, qb, kb, vb,
                                             qws, kws, vtws);
    attn_kernel<<<dim3(8, 12, 16), 256, 0, stream>>>(qws, kws, vtws, mask, cws);
    out_gemm<<<dim3(768), 512, 0, stream>>>(cws, wbuf, ob, hidden, xres);
    ln_kernel<<<dim3(4096), 256, 0, stream>>>(xres, gamma, beta, out);
}

// Round 10
// 300.703 us; speedup vs baseline: 1.0597x; 1.0597x over previous
//
// BertAttention MI355X kernel — r10 (logic identical to r8/r9; resubmitted
// after two harness-infra failures; comment touched to alter source hash).
#include <hip/hip_runtime.h>
#include <hip/hip_bf16.h>

#define B_  16
#define S_  1024
#define H_  768
#define NH_ 12
#define HD_ 64
#define BS_ (B_*S_)   // 16384
#define WROWS_ 589824 // 768*768 per weight matrix

typedef __bf16 bfx8 __attribute__((ext_vector_type(8)));
typedef __bf16 bfx4 __attribute__((ext_vector_type(4)));
typedef __bf16 bfx2 __attribute__((ext_vector_type(2)));
typedef float  f32x4 __attribute__((ext_vector_type(4)));
typedef float  f32x16 __attribute__((ext_vector_type(16)));
typedef unsigned u32x2 __attribute__((ext_vector_type(2)));
typedef unsigned u32x4 __attribute__((ext_vector_type(4)));

#define MFMA(a,b,c)   __builtin_amdgcn_mfma_f32_16x16x32_bf16(a,b,c,0,0,0)
#define MFMA32(a,b,c) __builtin_amdgcn_mfma_f32_32x32x16_bf16(a,b,c,0,0,0)

__device__ __forceinline__ float fast_exp2(float x) {
#if __has_builtin(__builtin_amdgcn_exp2f)
    return __builtin_amdgcn_exp2f(x);
#else
    return exp2f(x);
#endif
}

// async global->LDS, 16B per lane; LDS dest = wave-uniform base + lane*16
__device__ __forceinline__ void async_cp16(const __bf16* g, __bf16* l) {
    __builtin_amdgcn_global_load_lds(
        (const __attribute__((address_space(1))) unsigned int*)g,
        (__attribute__((address_space(3))) unsigned int*)l,
        16, 0, 0);
}

// pack two f32 -> one u32 of 2 bf16 (elem0 = low 16b)
__device__ __forceinline__ unsigned pk2(float a, float b) {
    bfx2 t; t[0] = (__bf16)a; t[1] = (__bf16)b;
    return __builtin_bit_cast(unsigned, t);
}

// v_permlane32_swap_b32: a.hi(lanes>=32) <-> b.lo(lanes<32).
__device__ __forceinline__ void pl32swap(unsigned &a, unsigned &b) {
#if __has_builtin(__builtin_amdgcn_permlane32_swap)
    u32x2 r = __builtin_amdgcn_permlane32_swap(a, b, 0, 0);
    a = r[0]; b = r[1];
#else
    asm volatile("v_permlane32_swap_b32 %0, %1" : "+v"(a), "+v"(b));
#endif
}

#define LOG2E 1.4426950408889634f
#define C1    (0.125f * LOG2E)     // score scale folded with log2(e)
#define SMAX  12.0f                // static softmax offset (exp2 domain)

// ---------------------------------------------------------------------------
// Pre-cast: hidden fp32 -> bf16 (hbf), [qw|kw|vw|ow] fp32 -> bf16 (wbuf).
// ---------------------------------------------------------------------------
__global__ __launch_bounds__(256) void precast(
    const float* __restrict__ hidden,
    const float* __restrict__ qw, const float* __restrict__ kw,
    const float* __restrict__ vw, const float* __restrict__ ow,
    __bf16* __restrict__ hbf, __bf16* __restrict__ wbuf)
{
    const int tid = threadIdx.x;
    const int bid = blockIdx.x;
    if (bid < 6144) {
        const long base = ((long)bid * 256 + tid) * 8;
        f32x4 a = *(const f32x4*)(hidden + base);
        f32x4 b = *(const f32x4*)(hidden + base + 4);
        bfx8 o;
        #pragma unroll
        for (int j = 0; j < 4; ++j) { o[j] = (__bf16)a[j]; o[4 + j] = (__bf16)b[j]; }
        *(bfx8*)(hbf + base) = o;
    } else {
        const long e = ((long)(bid - 6144) * 256 + tid) * 8;
        const int kind = (int)(e / WROWS_);
        const float* src = kind == 0 ? qw : kind == 1 ? kw : kind == 2 ? vw : ow;
        const long off = e - (long)kind * WROWS_;
        f32x4 a = *(const f32x4*)(src + off);
        f32x4 b = *(const f32x4*)(src + off + 4);
        bfx8 o;
        #pragma unroll
        for (int j = 0; j < 4; ++j) { o[j] = (__bf16)a[j]; o[4 + j] = (__bf16)b[j]; }
        *(bfx8*)(wbuf + e) = o;
    }
}

// ---------------------------------------------------------------------------
// Fused QKV GEMM. 128x128 tile, BK=64, swizzled global_load_lds staging.
// (round-4 serial-staging version — known-good)
// ---------------------------------------------------------------------------
__global__ __launch_bounds__(512, 4) void qkv_gemm(
    const __bf16* __restrict__ hbf, const __bf16* __restrict__ wbuf,
    const float* __restrict__ qb, const float* __restrict__ kb,
    const float* __restrict__ vb,
    __bf16* __restrict__ qo, __bf16* __restrict__ ko, __bf16* __restrict__ vto)
{
    __shared__ __bf16 smem[18432];      // 36864 B: As|Bs in [0,16384), Ts all
    __bf16* As = smem;                  // 8192 elems
    __bf16* Bs = smem + 8192;           // 8192 elems
    __bf16* Ts = smem;                  // epilogue: 8 waves x 2304 elems

    const int bid  = blockIdx.x;
    const int xcd  = bid & 7;
    const int slot = bid >> 3;          // 0..287
    const int xx   = slot >> 4;         // 0..17  (n-tile / weight panel)
    const int yy   = xcd * 16 + (slot & 15);   // 0..127 (m-tile)

    const int tid  = threadIdx.x;
    const int lane = tid & 63, wid = tid >> 6;
    const int quad = lane >> 4, l16 = lane & 15;
    const int n0g = xx * 128;
    const int m0  = yy * 128;
    const int wm = (wid & 3) * 32;      // s-slice (4)
    const int wn = (wid >> 2) * 64;     // d-slice (2)
    const int kind = xx / 6;            // 0=Q,1=K,2=V
    const int nl0  = n0g - kind * 768;

    // acc: Q/K -> [dt][st] flat dt*2+st ; V -> [st][dt] flat st*4+dt
    f32x4 acc[8];
    #pragma unroll
    for (int i = 0; i < 8; ++i)
        #pragma unroll
        for (int r = 0; r < 4; ++r) acc[i][r] = 0.0f;

    const int drow = lane >> 3;
    const int dcol = ((lane & 7) ^ (drow & 7)) * 8;
    const __bf16* Ag0 = hbf  + (long)(m0  + drow) * H_ + dcol;
    const __bf16* Bg0 = wbuf + (long)(n0g + drow) * H_ + dcol;
    const int swz = (l16 & 7);

    for (int kt = 0; kt < 12; ++kt) {
        __syncthreads();
        const int k0 = kt * 64;
        #pragma unroll
        for (int c = 0; c < 2; ++c) {
            const int cc = wid * 2 + c;       // chunk 0..15 (8 rows each)
            async_cp16(Ag0 + (long)cc * 8 * H_ + k0, As + cc * 512);
            async_cp16(Bg0 + (long)cc * 8 * H_ + k0, Bs + cc * 512);
        }
        __syncthreads();
        #pragma unroll
        for (int ks = 0; ks < 2; ++ks) {
            const int coff = ((ks * 4 + quad) ^ swz) * 8;
            bfx8 af[2], bb[4];
            #pragma unroll
            for (int t = 0; t < 2; ++t)
                af[t] = *(const bfx8*)(As + (wm + t * 16 + l16) * 64 + coff);
            #pragma unroll
            for (int t = 0; t < 4; ++t)
                bb[t] = *(const bfx8*)(Bs + (wn + t * 16 + l16) * 64 + coff);
            if (kind < 2) {
                #pragma unroll
                for (int dt = 0; dt < 4; ++dt)
                    #pragma unroll
                    for (int st = 0; st < 2; ++st)
                        acc[dt * 2 + st] = MFMA(bb[dt], af[st], acc[dt * 2 + st]);
            } else {
                #pragma unroll
                for (int st = 0; st < 2; ++st)
                    #pragma unroll
                    for (int dt = 0; dt < 4; ++dt)
                        acc[st * 4 + dt] = MFMA(af[st], bb[dt], acc[st * 4 + dt]);
            }
        }
    }

    __syncthreads();                    // As/Bs dead -> Ts reuse safe
    const int b  = m0 >> 10;
    const int hq = (nl0 + wn) >> 6;
    const int s_base = (m0 & 1023) + wm;

    if (kind < 2) {
        __bf16* Tw = Ts + wid * 2304;   // 32 x 72 tile [s][d]
        const float* bias = (kind == 0) ? qb : kb;
        __bf16* outp = (kind == 0) ? qo : ko;
        // acc[dt*2+st]: row=d=dt*16+quad*4+r, col=s=st*16+l16
        #pragma unroll
        for (int dt = 0; dt < 4; ++dt) {
            f32x4 bv = *(const f32x4*)(bias + nl0 + wn + dt * 16 + quad * 4);
            #pragma unroll
            for (int st = 0; st < 2; ++st) {
                bfx4 pk;
                #pragma unroll
                for (int r = 0; r < 4; ++r)
                    pk[r] = (__bf16)(acc[dt * 2 + st][r] + bv[r]);
                *(bfx4*)(Tw + (st * 16 + l16) * 72 + dt * 16 + quad * 4) = pk;
            }
        }
        __bf16* op = outp + ((((long)(b * NH_ + hq)) << 10) + s_base) * HD_;
        const int srow = lane >> 3, c8 = (lane & 7) * 8;
        #pragma unroll
        for (int i = 0; i < 4; ++i) {
            const int row = i * 8 + srow;                     // 0..31
            bfx8 vv = *(const bfx8*)(Tw + row * 72 + c8);
            *(bfx8*)(op + row * HD_ + c8) = vv;               // 1KB linear/instr
        }
    } else {
        __bf16* Tw = Ts + wid * 2304;   // 64 x 36 tile [d][s]
        // acc[st*4+dt]: row=s=st*16+quad*4+r, col=d=dt*16+l16
        #pragma unroll
        for (int dt = 0; dt < 4; ++dt) {
            const float bv = vb[nl0 + wn + dt * 16 + l16];
            #pragma unroll
            for (int st = 0; st < 2; ++st) {
                bfx4 pk;
                #pragma unroll
                for (int r = 0; r < 4; ++r)
                    pk[r] = (__bf16)(acc[st * 4 + dt][r] + bv);
                *(bfx4*)(Tw + (dt * 16 + l16) * 36 + st * 16 + quad * 4) = pk;
            }
        }
        __bf16* op = vto + (((long)(b * NH_ + hq) * HD_) << 10);
        #pragma unroll
        for (int i = 0; i < 4; ++i) {
            const int d = i * 16 + (lane >> 2);
            const int s8 = (lane & 3) * 8;
            bfx8 vv = *(const bfx8*)(Tw + d * 36 + s8);
            *(bfx8*)(op + ((long)d << 10) + s_base + s8) = vv;
        }
    }
}

// ---------------------------------------------------------------------------
// Attention, S^T formulation, 32x32x16 MFMA, P in registers.
//  - XCD-grouped 1-D grid (1536 blocks): xcd = bid&7 under round-robin
//    dispatch; each XCD owns 24 whole heads (hIdx = xcd*24 + slot/8,
//    qc = slot&7). All 8 sharers of one head's K/V (256 KB) run consecutively
//    on ONE XCD -> fetched once into its 4 MB L2, reused 8x.
//  - double-buffered 64-key staging (r4 proven structure): prefetch kt+1
//    right after the barrier, drain lands after a full compute phase.
//  - LDS 36 KB -> 4 blocks/CU co-resident; launch_bounds(256,4).
// ---------------------------------------------------------------------------
__global__ __launch_bounds__(256, 4) void attn_kernel(
    const __bf16* __restrict__ q, const __bf16* __restrict__ k,
    const __bf16* __restrict__ vT, const float* __restrict__ mask,
    __bf16* __restrict__ ctx)
{
    __shared__ __bf16 Ks[2][4096];      // [buf][64 key][64 d] swz  16 KB
    __shared__ __bf16 Vs[2][4096];      // [buf][64 d][64 key] swz  16 KB
    __shared__ float  Ms[1024];         // mask*log2e - SMAX          4 KB

    const int bid  = blockIdx.x;
    const int xcd  = bid & 7;           // XCD under round-robin dispatch
    const int slot = bid >> 3;          // 0..191 per-XCD issue order
    const int hIdx = xcd * 24 + (slot >> 3);   // 0..191 global head
    const int qc   = slot & 7;
    const int b    = hIdx / NH_;
    const int h    = hIdx - b * NH_;

    const int tid  = threadIdx.x;
    const int lane = tid & 63, wid = tid >> 6;       // wid 0..3
    const int l32  = lane & 31, hi = lane >> 5;

    const long base = ((long)hIdx) << 16;            // * S_ * HD_
    const __bf16* qh = q  + base;
    const __bf16* kh = k  + base;
    const __bf16* vh = vT + base;
    const float*  mb = mask + b * S_;

    #pragma unroll
    for (int i = 0; i < 4; ++i)
        Ms[tid + i * 256] = mb[tid + i * 256] * LOG2E - SMAX;

    const int qrow = qc * 128 + wid * 32 + l32;
    bfx8 qf[4];                         // B-frag: n=q=l32, k=ks*16+hi*8+0..7
    #pragma unroll
    for (int ks = 0; ks < 4; ++ks)
        qf[ks] = *(const bfx8*)(qh + (long)qrow * HD_ + ks * 16 + hi * 8);

    f32x16 o[2];                        // [dtile]: d=dtile*32+(r&3)+8*(r>>2)+4hi
    #pragma unroll
    for (int dt = 0; dt < 2; ++dt)
        #pragma unroll
        for (int r = 0; r < 16; ++r) o[dt][r] = 0.0f;
    f32x4 lacc4 = { 0.0f, 0.0f, 0.0f, 0.0f };

    // staging geometry: chunk = 1KB (8 rows x 128B), row-local swizzle
    const int r8  = lane >> 3;                 // row within chunk (0..7)
    const int c8  = ((lane & 7) ^ r8) * 8;     // pre-swizzled 16B col group
    const int sw5 = l32 & 7;

    // prologue: stage kt=0 into buf 0 (chunks cc = wid*2+c, 0..7)
    #pragma unroll
    for (int c = 0; c < 2; ++c) {
        const int cc = wid * 2 + c;
        async_cp16(kh + (long)(cc * 8 + r8) * HD_ + c8, &Ks[0][cc * 512]);
        async_cp16(vh + (long)(cc * 8 + r8) * S_  + c8, &Vs[0][cc * 512]);
    }

    for (int kt = 0; kt < 16; ++kt) {
        __syncthreads();                // vmcnt(0) drain: buf[kt&1] ready
        const __bf16* Kb = Ks[kt & 1];
        const __bf16* Vb = Vs[kt & 1];
        if (kt < 15) {                  // prefetch kt+1 into the other buffer
            const int kn = kt + 1;
            #pragma unroll
            for (int c = 0; c < 2; ++c) {
                const int cc = wid * 2 + c;
                async_cp16(kh + (long)(kn * 64 + cc * 8 + r8) * HD_ + c8,
                           &Ks[kn & 1][cc * 512]);
                async_cp16(vh + (long)(cc * 8 + r8) * S_ + kn * 64 + c8,
                           &Vs[kn & 1][cc * 512]);
            }
        }

        #pragma unroll
        for (int t = 0; t < 2; ++t) {           // 32-key tiles
            // ---- QK^T: 4 MFMA over dk=64 ----
            f32x16 sc;
            #pragma unroll
            for (int r = 0; r < 16; ++r) sc[r] = 0.0f;
            __builtin_amdgcn_s_setprio(1);
            #pragma unroll
            for (int ks = 0; ks < 4; ++ks) {
                bfx8 kf = *(const bfx8*)(Kb + (t * 32 + l32) * 64 +
                                         (((ks * 2 + hi) ^ sw5) * 8));
                sc = MFMA32(kf, qf[ks], sc);
            }
            __builtin_amdgcn_s_setprio(0);

            // ---- softmax (static offset) + pack to bf16 words ----
            unsigned c[8];
            #pragma unroll
            for (int j = 0; j < 4; ++j) {
                const f32x4 mv = *(const f32x4*)(&Ms[kt * 64 + t * 32 +
                                                    j * 8 + hi * 4]);
                f32x4 p;
                p[0] = fast_exp2(sc[4*j+0] * C1 + mv[0]);
                p[1] = fast_exp2(sc[4*j+1] * C1 + mv[1]);
                p[2] = fast_exp2(sc[4*j+2] * C1 + mv[2]);
                p[3] = fast_exp2(sc[4*j+3] * C1 + mv[3]);
                lacc4 += p;
                c[2*j]   = pk2(p[0], p[1]);
                c[2*j+1] = pk2(p[2], p[3]);
            }
            // redistribute lane-halves: B-frag kslice0 = (c0..c3),
            // kslice1 = (c4..c7)
            pl32swap(c[0], c[2]);
            pl32swap(c[1], c[3]);
            pl32swap(c[4], c[6]);
            pl32swap(c[5], c[7]);
            u32x4 pw0 = { c[0], c[1], c[2], c[3] };
            u32x4 pw1 = { c[4], c[5], c[6], c[7] };
            bfx8 pb[2];
            pb[0] = __builtin_bit_cast(bfx8, pw0);
            pb[1] = __builtin_bit_cast(bfx8, pw1);

            // ---- PV: o[dtile] += V^T x P, 2 kslices of 16 keys ----
            __builtin_amdgcn_s_setprio(1);
            #pragma unroll
            for (int s = 0; s < 2; ++s) {
                const int ksl = t * 2 + s;              // 0..3
                #pragma unroll
                for (int dt = 0; dt < 2; ++dt) {
                    bfx8 vf = *(const bfx8*)(Vb + (dt * 32 + l32) * 64 +
                                             (((ksl * 2 + hi) ^ sw5) * 8));
                    o[dt] = MFMA32(vf, pb[s], o[dt]);
                }
            }
            __builtin_amdgcn_s_setprio(0);
        }
    }

    // denom: lane covers half the keys for its q; partner lane^32 the rest
    float lacc = (lacc4[0] + lacc4[1]) + (lacc4[2] + lacc4[3]);
    lacc += __shfl_xor(lacc, 32);
    const float linv = 1.0f / lacc;

    __bf16* cp = ctx + ((long)(b << 10) + qrow) * H_ + h * HD_;
    #pragma unroll
    for (int dt = 0; dt < 2; ++dt) {
        #pragma unroll
        for (int j = 0; j < 4; ++j) {
            bfx4 ov;
            #pragma unroll
            for (int r = 0; r < 4; ++r)
                ov[r] = (__bf16)(o[dt][4*j+r] * linv);
            *(bfx4*)(cp + dt * 32 + j * 8 + hi * 4) = ov;
        }
    }
}

// ---------------------------------------------------------------------------
// Output projection + residual. 8 waves x (32m x 64n), XCD-chunked map.
// (round-4 serial-staging version — known-good)
// ---------------------------------------------------------------------------
__global__ __launch_bounds__(512, 4) void out_gemm(
    const __bf16* __restrict__ ctx, const __bf16* __restrict__ wbuf,
    const float* __restrict__ ob, const float* __restrict__ hidden,
    float* __restrict__ xres)
{
    __shared__ __bf16 As[128 * 64];
    __shared__ __bf16 Bs[128 * 64];

    const int bid  = blockIdx.x;
    const int xcd  = bid & 7;
    const int slot = bid >> 3;          // 0..95
    const int xx   = slot >> 4;         // 0..5
    const int yy   = xcd * 16 + (slot & 15);

    const int tid  = threadIdx.x;
    const int lane = tid & 63, wid = tid >> 6;
    const int quad = lane >> 4, l16 = lane & 15;
    const int n0 = xx * 128;
    const int m0 = yy * 128;
    const int wm = (wid & 3) * 32;
    const int wn = (wid >> 2) * 64;

    f32x4 acc[2][4];
    #pragma unroll
    for (int i = 0; i < 2; ++i)
        #pragma unroll
        for (int j = 0; j < 4; ++j)
            #pragma unroll
            for (int r = 0; r < 4; ++r) acc[i][j][r] = 0.0f;

    const int drow = lane >> 3;
    const int dcol = ((lane & 7) ^ (drow & 7)) * 8;
    const __bf16* Ag0 = ctx  + (long)(m0 + drow) * H_ + dcol;
    const __bf16* Bg0 = wbuf + (long)(3 * 768 + n0 + drow) * H_ + dcol;
    const int swz = (l16 & 7);

    for (int kt = 0; kt < 12; ++kt) {
        __syncthreads();
        const int k0 = kt * 64;
        #pragma unroll
        for (int c = 0; c < 2; ++c) {
            const int cc = wid * 2 + c;
            async_cp16(Ag0 + (long)cc * 8 * H_ + k0, As + cc * 512);
            async_cp16(Bg0 + (long)cc * 8 * H_ + k0, Bs + cc * 512);
        }
        __syncthreads();
        #pragma unroll
        for (int ks = 0; ks < 2; ++ks) {
            const int coff = ((ks * 4 + quad) ^ swz) * 8;
            bfx8 af[2], bb[4];
            #pragma unroll
            for (int t = 0; t < 2; ++t)
                af[t] = *(const bfx8*)(As + (wm + t * 16 + l16) * 64 + coff);
            #pragma unroll
            for (int t = 0; t < 4; ++t)
                bb[t] = *(const bfx8*)(Bs + (wn + t * 16 + l16) * 64 + coff);
            #pragma unroll
            for (int mt = 0; mt < 2; ++mt)
                #pragma unroll
                for (int nt = 0; nt < 4; ++nt)
                    acc[mt][nt] = MFMA(af[mt], bb[nt], acc[mt][nt]);
        }
    }

    #pragma unroll
    for (int nt = 0; nt < 4; ++nt) {
        const int n = n0 + wn + nt * 16 + l16;
        const float bv = ob[n];
        #pragma unroll
        for (int mt = 0; mt < 2; ++mt) {
            #pragma unroll
            for (int r = 0; r < 4; ++r) {
                const int m = m0 + wm + mt * 16 + quad * 4 + r;
                const long idx = (long)m * H_ + n;
                xres[idx] = acc[mt][nt][r] + bv + hidden[idx];
            }
        }
    }
}

// ---------------------------------------------------------------------------
// LayerNorm over H=768, wave per row
// ---------------------------------------------------------------------------
__global__ __launch_bounds__(256) void ln_kernel(
    const float* __restrict__ xres, const float* __restrict__ gamma,
    const float* __restrict__ beta, float* __restrict__ out)
{
    const int tid = threadIdx.x, lane = tid & 63, wid = tid >> 6;
    const long row = (long)blockIdx.x * 4 + wid;
    const float* xr = xres + row * H_;

    f32x4 xv[3];
    float sum = 0.0f, sumsq = 0.0f;
    #pragma unroll
    for (int c = 0; c < 3; ++c) {
        xv[c] = *(const f32x4*)(xr + c * 256 + lane * 4);
        #pragma unroll
        for (int j = 0; j < 4; ++j) { sum += xv[c][j]; sumsq += xv[c][j] * xv[c][j]; }
    }
    #pragma unroll
    for (int off = 1; off < 64; off <<= 1) {
        sum   += __shfl_xor(sum, off);
        sumsq += __shfl_xor(sumsq, off);
    }
    const float mean = sum * (1.0f / 768.0f);
    const float var  = sumsq * (1.0f / 768.0f) - mean * mean;
    const float rstd = rsqrtf(var + 1e-12f);

    float* orow = out + row * H_;
    #pragma unroll
    for (int c = 0; c < 3; ++c) {
        f32x4 g  = *(const f32x4*)(gamma + c * 256 + lane * 4);
        f32x4 bt = *(const f32x4*)(beta  + c * 256 + lane * 4);
        f32x4 ov;
        #pragma unroll
        for (int j = 0; j < 4; ++j) ov[j] = (xv[c][j] - mean) * rstd * g[j] + bt[j];
        *(f32x4*)(orow + c * 256 + lane * 4) = ov;
    }
}

extern "C" void kernel_launch(void* const* d_in, const int* in_sizes, int n_in,
                              void* d_out, int out_size, void* d_ws, size_t ws_size,
                              hipStream_t stream)
{
    const float* hidden = (const float*)d_in[0];
    const float* mask   = (const float*)d_in[1];
    const float* qw = (const float*)d_in[2];
    const float* qb = (const float*)d_in[3];
    const float* kw = (const float*)d_in[4];
    const float* kb = (const float*)d_in[5];
    const float* vw = (const float*)d_in[6];
    const float* vb = (const float*)d_in[7];
    const float* ow = (const float*)d_in[8];
    const float* ob = (const float*)d_in[9];
    const float* gamma = (const float*)d_in[10];
    const float* beta  = (const float*)d_in[11];
    float* out = (float*)d_out;

    // ws layout (96 MB): [0,24) hbf->ctx alias; [24,48) q; [48,72) k; [72,96) vt
    // xres fp32 aliases [24,72). wbuf bf16 weights live in d_out until ln.
    char* ws = (char*)d_ws;
    const size_t SZB = (size_t)BS_ * H_ * 2;     // 25,165,824 B per bf16 buffer
    __bf16* hbf  = (__bf16*)ws;
    __bf16* qws  = (__bf16*)(ws + SZB);
    __bf16* kws  = (__bf16*)(ws + 2 * SZB);
    __bf16* vtws = (__bf16*)(ws + 3 * SZB);
    __bf16* cws  = hbf;                          // ctx aliases hbf
    float*  xres = (float*)(ws + SZB);           // aliases q,k
    __bf16* wbuf = (__bf16*)d_out;               // scratch inside output buffer

    precast<<<dim3(7296), 256, 0, stream>>>(hidden, qw, kw, vw, ow, hbf, wbuf);
    qkv_gemm<<<dim3(2304), 512, 0, stream>>>(hbf, wbuf, qb, kb, vb,
                                             qws, kws, vtws);
    attn_kernel<<<dim3(1536), 256, 0, stream>>>(qws, kws, vtws, mask, cws);
    out_gemm<<<dim3(768), 512, 0, stream>>>(cws, wbuf, ob, hidden, xres);
    ln_kernel<<<dim3(4096), 256, 0, stream>>>(xres, gamma, beta, out);
}